// Round 1
// 688.998 us; speedup vs baseline: 1.0901x; 1.0901x over previous
//
#include <hip/hip_runtime.h>
#include <cstdint>

typedef _Float16 half4v __attribute__((ext_vector_type(4)));
typedef _Float16 half8v __attribute__((ext_vector_type(8)));
typedef __fp16   fp16x2 __attribute__((ext_vector_type(2)));
typedef float    f32x4v __attribute__((ext_vector_type(4)));

#define DIM    4096
#define SEQ    2048
#define NBATCH 2
#define NHEAD  32
#define NKVH   8
#define HDIM   128
#define MROWS  (NBATCH*SEQ)   // 4096
#define QKV_N  6144           // q(4096) | k(1024) | v(1024)
#define KOFF   4096
#define VOFF   5120

// async global->LDS, 16B per lane; LDS dest is wave-uniform base + lane*16
__device__ __forceinline__ void gl_lds16(const _Float16* g, _Float16* l) {
  __builtin_amdgcn_global_load_lds(
      (const __attribute__((address_space(1))) void*)g,
      (__attribute__((address_space(3))) void*)l, 16, 0, 0);
}

// ---------------- fp32 -> fp16 convert ----------------
__global__ __launch_bounds__(256) void cvt_kernel(const float* __restrict__ in,
                                                  _Float16* __restrict__ out, int n8) {
  int stride = gridDim.x * blockDim.x;
  for (int i = blockIdx.x * blockDim.x + threadIdx.x; i < n8; i += stride) {
    const float4* p = (const float4*)(in + (size_t)i * 8);
    float4 a = p[0], b = p[1];
    half8v h;
    h[0] = (_Float16)a.x; h[1] = (_Float16)a.y; h[2] = (_Float16)a.z; h[3] = (_Float16)a.w;
    h[4] = (_Float16)b.x; h[5] = (_Float16)b.y; h[6] = (_Float16)b.z; h[7] = (_Float16)b.w;
    *(half8v*)(out + (size_t)i * 8) = h;
  }
}

// ---------------- GEMM: C[M,N] = A[M,K] * B[N,K]^T (fp16 in, f32 acc) ----------------
// 256x256 8-phase template (learn_hip m201): BK=64, 8 waves (2Mx4N), 512 thr,
// 128 KiB LDS double-buffer, row-XOR LDS swizzle, counted vmcnt(6), setprio.
// Requires: M%256==0, N%256==0, K%128==0 (nkt even), grid%8==0 for XCD swizzle.

// raw barrier, compiler-fenced so loads/stores cannot migrate across it
#define SBAR() do { asm volatile("" ::: "memory"); \
                    __builtin_amdgcn_s_barrier();  \
                    asm volatile("" ::: "memory"); } while (0)
#define LGK0() asm volatile("s_waitcnt lgkmcnt(0)" ::: "memory")
#define VM6()  asm volatile("s_waitcnt vmcnt(6)" ::: "memory")
#define VM0()  asm volatile("s_waitcnt vmcnt(0)" ::: "memory")

// stage one 128-row half-tile (2 x gl_lds per thread). LDS dest linear;
// global source column pre-swizzled by (row&7) so swizzled ds_read matches.
#define STAGE_HALF(Gm, rowbase, kidx, h, buf) do {                                   \
    gl_lds16((Gm) + (size_t)((rowbase) + (h)*128 + srow) * K + (kidx)*64 + sslot8,   \
             (buf) + (h)*8192 + w*512);                                              \
    gl_lds16((Gm) + (size_t)((rowbase) + (h)*128 + 64 + srow) * K + (kidx)*64 + sslot8, \
             (buf) + (h)*8192 + 4096 + w*512);                                       \
  } while (0)

#define MFMA_Q(hm, hn, bf)                                                   \
    _Pragma("unroll") for (int kk = 0; kk < 2; ++kk)                         \
      _Pragma("unroll") for (int mi = 0; mi < 4; ++mi)                       \
        _Pragma("unroll") for (int ni = 0; ni < 2; ++ni)                     \
          acc[(hm) * 4 + mi][(hn) * 2 + ni] =                                \
              __builtin_amdgcn_mfma_f32_16x16x32_f16(                        \
                  a[mi][kk], bf[ni][kk], acc[(hm) * 4 + mi][(hn) * 2 + ni], 0, 0, 0)

// One K-tile = 4 phases (16 MFMA each, one output quadrant per phase).
// ds_reads per phase: 12 / 4 / 8 / 0 (A0+B0, B1, A1, none - regs reused).
// Staging: ph1 -> Ah1(k+1) into other buffer; ph3 -> Bh0,Bh1(k+2); ph4 -> Ah0(k+2)
// into CURRENT buffer (regions proven free: B after ph2, A after ph3).
// vmcnt(6) at ph4 = 3 half-tiles (6 loads) in flight; guarantees k+1 fully landed.
#define KSTEP(kcur, AC, BC, AN)                                              \
  do {                                                                       \
    const int k_ = (kcur);                                                   \
    half8v a[4][2], b0[2][2], b1[2][2];                                      \
    /* ---- phase 1: quadrant (m0,n0) */                                     \
    _Pragma("unroll") for (int mi = 0; mi < 4; ++mi)                         \
      _Pragma("unroll") for (int kk = 0; kk < 2; ++kk)                       \
        a[mi][kk] = *(const half8v*)((AC) + (wm * 128 + mi * 16 + li) * 64 + \
                                     (((kk * 4 + g) ^ li7) * 8));            \
    _Pragma("unroll") for (int ni = 0; ni < 2; ++ni)                         \
      _Pragma("unroll") for (int kk = 0; kk < 2; ++kk)                       \
        b0[ni][kk] = *(const half8v*)((BC) + (wn * 64 + ni * 16 + li) * 64 + \
                                      (((kk * 4 + g) ^ li7) * 8));           \
    if (k_ + 1 < nkt) STAGE_HALF(A, bm, k_ + 1, 1, (AN));                    \
    SBAR(); LGK0();                                                          \
    __builtin_amdgcn_s_setprio(1);                                           \
    MFMA_Q(0, 0, b0);                                                        \
    __builtin_amdgcn_s_setprio(0);                                           \
    SBAR();                                                                  \
    /* ---- phase 2: quadrant (m0,n1) */                                     \
    _Pragma("unroll") for (int ni = 0; ni < 2; ++ni)                         \
      _Pragma("unroll") for (int kk = 0; kk < 2; ++kk)                       \
        b1[ni][kk] = *(const half8v*)((BC) + (wn * 64 + 32 + ni * 16 + li) * 64 + \
                                      (((kk * 4 + g) ^ li7) * 8));           \
    SBAR(); LGK0();                                                          \
    __builtin_amdgcn_s_setprio(1);                                           \
    MFMA_Q(0, 1, b1);                                                        \
    __builtin_amdgcn_s_setprio(0);                                           \
    SBAR();                                                                  \
    /* ---- phase 3: quadrant (m1,n1); stage B(k+2) into current buf */      \
    _Pragma("unroll") for (int mi = 0; mi < 4; ++mi)                         \
      _Pragma("unroll") for (int kk = 0; kk < 2; ++kk)                       \
        a[mi][kk] = *(const half8v*)((AC) + (wm * 128 + 64 + mi * 16 + li) * 64 + \
                                     (((kk * 4 + g) ^ li7) * 8));            \
    if (k_ + 2 < nkt) {                                                      \
      STAGE_HALF(B, bn, k_ + 2, 0, (BC));                                    \
      STAGE_HALF(B, bn, k_ + 2, 1, (BC));                                    \
    }                                                                        \
    SBAR(); LGK0();                                                          \
    __builtin_amdgcn_s_setprio(1);                                           \
    MFMA_Q(1, 1, b1);                                                        \
    __builtin_amdgcn_s_setprio(0);                                           \
    SBAR();                                                                  \
    /* ---- phase 4: quadrant (m1,n0); stage Ah0(k+2); counted vmcnt */      \
    if (k_ + 2 < nkt) STAGE_HALF(A, bm, k_ + 2, 0, (AC));                    \
    SBAR();                                                                  \
    __builtin_amdgcn_s_setprio(1);                                           \
    MFMA_Q(1, 0, b0);                                                        \
    __builtin_amdgcn_s_setprio(0);                                           \
    if (k_ + 2 < nkt) { VM6(); } else if (k_ + 1 < nkt) { VM0(); }           \
    SBAR();                                                                  \
  } while (0)

template<int OUTF16>
__global__ __launch_bounds__(512, 2) void gemm256(const _Float16* __restrict__ A,
                                                  const _Float16* __restrict__ B,
                                                  void* __restrict__ Cp,
                                                  int N, int K, int nbx) {
  __shared__ __align__(16) _Float16 As[2][256 * 64];
  __shared__ __align__(16) _Float16 Bs[2][256 * 64];
  const int tid = threadIdx.x, lane = tid & 63, w = tid >> 6;
  const int g = lane >> 4, li = lane & 15, li7 = lane & 7;
  const int wm = w >> 2, wn = w & 3;          // 2x4 wave grid, 128x64 out per wave
  // XCD-aware block swizzle (bijective: grid % 8 == 0 for both launches)
  const int nwg = gridDim.x, orig = blockIdx.x;
  const int wgid = (nwg & 7) ? orig : ((orig & 7) * (nwg >> 3) + (orig >> 3));
  const int bm = (wgid / nbx) * 256, bn = (wgid % nbx) * 256;
  const int srow = tid >> 3;                              // staging row 0..63
  const int sslot8 = ((lane & 7) ^ ((lane >> 3) & 7)) * 8; // pre-swizzled src col
  const int nkt = K >> 6;
  _Float16* As0 = &As[0][0]; _Float16* As1 = &As[1][0];
  _Float16* Bs0 = &Bs[0][0]; _Float16* Bs1 = &Bs[1][0];

  f32x4v acc[8][4] = {};

  // ---- prologue: k=0 all 4 halves -> buf0; k=1 Bh0,Bh1,Ah0 -> buf1 (3 in flight)
  STAGE_HALF(A, bm, 0, 0, As0);
  STAGE_HALF(A, bm, 0, 1, As0);
  STAGE_HALF(B, bn, 0, 0, Bs0);
  STAGE_HALF(B, bn, 0, 1, Bs0);
  if (nkt > 1) {
    STAGE_HALF(B, bn, 1, 0, Bs1);
    STAGE_HALF(B, bn, 1, 1, Bs1);
    STAGE_HALF(A, bm, 1, 0, As1);
    VM6();
  } else {
    VM0();
  }
  SBAR();

  for (int k = 0; k < nkt; k += 2) {   // nkt even (K % 128 == 0)
    KSTEP(k,     As0, Bs0, As1);
    KSTEP(k + 1, As1, Bs1, As0);
  }

  // ---- epilogue: C/D layout col=li, row=g*4+j
  const int r0 = bm + wm * 128 + g * 4;
  const int c0 = bn + wn * 64 + li;
#pragma unroll
  for (int mi = 0; mi < 8; ++mi)
#pragma unroll
    for (int ni = 0; ni < 4; ++ni)
#pragma unroll
      for (int j = 0; j < 4; ++j) {
        size_t idx = (size_t)(r0 + mi * 16 + j) * N + (c0 + ni * 16);
        if (OUTF16) ((_Float16*)Cp)[idx] = (_Float16)acc[mi][ni][j];
        else        ((float*)Cp)[idx]    = acc[mi][ni][j];
      }
}

// ---------------- LayerNorm (full row) + RoPE, in-place on strided fp16 view ----------------
template<int E>
__global__ __launch_bounds__(256) void ln_rope(_Float16* __restrict__ t, int ldt,
                                               const float* __restrict__ gw,
                                               const float* __restrict__ gb,
                                               const float* __restrict__ fc) {
  constexpr int EPT = E / 256;
  const int row = blockIdx.x;
  const int s = row & (SEQ - 1);
  const int tid = threadIdx.x, lane = tid & 63, w = tid >> 6;
  _Float16* rp = t + (size_t)row * ldt + tid * EPT;
  float v[EPT];
#pragma unroll
  for (int i = 0; i < EPT; i += 4) {
    half4v hv = *(const half4v*)(rp + i);
    v[i] = (float)hv[0]; v[i+1] = (float)hv[1]; v[i+2] = (float)hv[2]; v[i+3] = (float)hv[3];
  }
  float sum = 0.f, ssq = 0.f;
#pragma unroll
  for (int i = 0; i < EPT; ++i) { sum += v[i]; ssq += v[i] * v[i]; }
#pragma unroll
  for (int off = 1; off < 64; off <<= 1) { sum += __shfl_xor(sum, off); ssq += __shfl_xor(ssq, off); }
  __shared__ float red[8];
  if (lane == 0) { red[w] = sum; red[4 + w] = ssq; }
  __syncthreads();
  sum = red[0] + red[1] + red[2] + red[3];
  ssq = red[4] + red[5] + red[6] + red[7];
  const float mu = sum * (1.0f / E);
  const float rstd = rsqrtf(ssq * (1.0f / E) - mu * mu + 1e-5f);
  float ov[EPT];
#pragma unroll
  for (int i = 0; i < EPT; i += 2) {
    int e = tid * EPT + i;
    int hd = e & (HDIM - 1);
    float2 cs = *(const float2*)(fc + (size_t)s * HDIM + (hd >> 1) * 2);
    float a = (v[i]   - mu) * rstd * gw[e]   + gb[e];
    float b = (v[i+1] - mu) * rstd * gw[e+1] + gb[e+1];
    ov[i]   = a * cs.x - b * cs.y;
    ov[i+1] = a * cs.y + b * cs.x;
  }
#pragma unroll
  for (int i = 0; i < EPT; i += 4) {
    half4v hv;
    hv[0] = (_Float16)ov[i];   hv[1] = (_Float16)ov[i+1];
    hv[2] = (_Float16)ov[i+2]; hv[3] = (_Float16)ov[i+3];
    *(half4v*)(rp + i) = hv;
  }
}

// ---------------- Flash attention v3 ----------------
__global__ __launch_bounds__(256, 2) void attn_kernel(const _Float16* __restrict__ QKV,
                                                      _Float16* __restrict__ Oa) {
  __shared__ __align__(16) _Float16 Ksh[2][64 * 128];  // row-swizzled, double-buffered
  __shared__ __align__(16) char Vt[128 * 128];         // V^T, swizzled 16B slots
  const int tid = threadIdx.x, lane = tid & 63, w = tid >> 6;
  const int g = lane >> 4, li = lane & 15;
  const int blk = blockIdx.x;
  const int qt = blk & 31, h = (blk >> 5) & 31, b = blk >> 10;
  const int kvh = h >> 2;
  const size_t LD = QKV_N;
  const _Float16* Qb = QKV + (size_t)(b * SEQ) * LD + h * HDIM;
  const _Float16* Kb = QKV + (size_t)(b * SEQ) * LD + KOFF + kvh * HDIM;
  const _Float16* Vb = QKV + (size_t)(b * SEQ) * LD + VOFF + kvh * HDIM;
  const int qrow = qt * 64 + w * 16 + li;
  half8v qf[4];
#pragma unroll
  for (int kk = 0; kk < 4; ++kk) {
    half8v q0 = *(const half8v*)(Qb + (size_t)qrow * LD + kk * 32 + g * 8);
#pragma unroll
    for (int e = 0; e < 8; ++e) q0[e] = q0[e] * (_Float16)0.08838834764831845f;
    qf[kk] = q0;
  }
  float mrow = -1e30f, lrow = 0.f;
  f32x4v oacc[8] = {};
  uint4 va[2], vb2[2];
  const int lg = lane >> 4;
  const int gbit = (lane >> 5) & 1;
#pragma unroll
  for (int i = 0; i < 4; ++i) {
    int chunk = i * 4 + w;
    int r = chunk * 4 + lg;
    int sc8 = ((lane & 15) ^ (r & 7)) * 8;
    gl_lds16(Kb + (size_t)r * LD + sc8, Ksh[0] + chunk * 512);
  }
#pragma unroll
  for (int i = 0; i < 2; ++i) {
    int p = tid + 256 * i; int v2 = p >> 4, c8 = p & 15;
    va[i]  = *(const uint4*)(Vb + (size_t)(v2 * 2)     * LD + c8 * 8);
    vb2[i] = *(const uint4*)(Vb + (size_t)(v2 * 2 + 1) * LD + c8 * 8);
  }
  const int NT = SEQ / 64;
  for (int kt = 0; kt < NT; ++kt) {
    __syncthreads();
#pragma unroll
    for (int i = 0; i < 2; ++i) {
      int p = tid + 256 * i; int v2 = p >> 4, c8 = p & 15;
      const uint32_t* a0 = (const uint32_t*)&va[i];
      const uint32_t* a1 = (const uint32_t*)&vb2[i];
      int slot = v2 >> 2, bofs = (v2 & 3) << 2;
#pragma unroll
      for (int wi = 0; wi < 4; ++wi) {
        uint32_t ev = __builtin_amdgcn_perm(a1[wi], a0[wi], 0x05040100u);
        uint32_t od = __builtin_amdgcn_perm(a1[wi], a0[wi], 0x07060302u);
        int hd0 = c8 * 8 + 2 * wi, hd1 = hd0 + 1;
        int k0 = ((hd0 >> 3) ^ hd0) & 7, k1 = ((hd1 >> 3) ^ hd1) & 7;
        *(uint32_t*)(Vt + hd0 * 128 + ((slot ^ k0) << 4) + bofs) = ev;
        *(uint32_t*)(Vt + hd1 * 128 + ((slot ^ k1) << 4) + bofs) = od;
      }
    }
    __syncthreads();
    if (kt + 1 < NT) {
#pragma unroll
      for (int i = 0; i < 2; ++i) {
        int p = tid + 256 * i; int v2 = p >> 4, c8 = p & 15;
        va[i]  = *(const uint4*)(Vb + (size_t)((kt + 1) * 64 + v2 * 2)     * LD + c8 * 8);
        vb2[i] = *(const uint4*)(Vb + (size_t)((kt + 1) * 64 + v2 * 2 + 1) * LD + c8 * 8);
      }
    }
    const _Float16* Kcur = Ksh[kt & 1];
    f32x4v sc[4] = {};
    __builtin_amdgcn_s_setprio(1);
#pragma unroll
    for (int kk = 0; kk < 4; ++kk) {
#pragma unroll
      for (int ni = 0; ni < 4; ++ni) {
        half8v kf = *(const half8v*)(Kcur + (16 * ni + li) * 128 + ((4 * kk + g) ^ (li & 7)) * 8);
        sc[ni] = __builtin_amdgcn_mfma_f32_16x16x32_f16(kf, qf[kk], sc[ni], 0, 0, 0);
      }
    }
    __builtin_amdgcn_s_setprio(0);
    if (kt + 1 < NT) {
      _Float16* Knxt = Ksh[(kt + 1) & 1];
#pragma unroll
      for (int i = 0; i < 4; ++i) {
        int chunk = i * 4 + w;
        int r = chunk * 4 + lg;
        int sc8 = ((lane & 15) ^ (r & 7)) * 8;
        gl_lds16(Kb + (size_t)((kt + 1) * 64 + r) * LD + sc8, Knxt + chunk * 512);
      }
    }
    float m16 = sc[0][0];
#pragma unroll
    for (int ni = 0; ni < 4; ++ni) {
      m16 = fmaxf(m16, fmaxf(fmaxf(sc[ni][0], sc[ni][1]), fmaxf(sc[ni][2], sc[ni][3])));
    }
    m16 = fmaxf(m16, __shfl_xor(m16, 16));
    m16 = fmaxf(m16, __shfl_xor(m16, 32));
    if (!__all(m16 - mrow <= 8.0f)) {
      const float mn = fmaxf(mrow, m16);
      const float sfo = __expf(mrow - mn);
      mrow = mn;
      lrow *= sfo;
      float sfj[4];
#pragma unroll
      for (int j = 0; j < 4; ++j) sfj[j] = __shfl(sfo, (lane & 48) | (4 * g + j));
#pragma unroll
      for (int nio = 0; nio < 8; ++nio) {
        oacc[nio][0] *= sfj[0]; oacc[nio][1] *= sfj[1];
        oacc[nio][2] *= sfj[2]; oacc[nio][3] *= sfj[3];
      }
    }
    float pp[4][4];
    float rs = 0.f;
#pragma unroll
    for (int ni = 0; ni < 4; ++ni)
#pragma unroll
      for (int j = 0; j < 4; ++j) { float pv = __expf(sc[ni][j] - mrow); pp[ni][j] = pv; rs += pv; }
    rs += __shfl_xor(rs, 16); rs += __shfl_xor(rs, 32);
    lrow += rs;
    uint32_t u[4][2];
#pragma unroll
    for (int ni = 0; ni < 4; ++ni) {
      fp16x2 p0 = __builtin_amdgcn_cvt_pkrtz(pp[ni][0], pp[ni][1]);
      fp16x2 p1 = __builtin_amdgcn_cvt_pkrtz(pp[ni][2], pp[ni][3]);
      u[ni][0] = *(uint32_t*)&p0;
      u[ni][1] = *(uint32_t*)&p1;
    }
#pragma unroll
    for (int kk = 0; kk < 2; ++kk) {
      uint32_t own0 = gbit ? u[2*kk+1][0] : u[2*kk][0];
      uint32_t own1 = gbit ? u[2*kk+1][1] : u[2*kk][1];
      uint32_t oth0 = gbit ? u[2*kk][0]   : u[2*kk+1][0];
      uint32_t oth1 = gbit ? u[2*kk][1]   : u[2*kk+1][1];
      uint32_t r16_0 = (uint32_t)__shfl_xor((int)own0, 16);
      uint32_t r16_1 = (uint32_t)__shfl_xor((int)own1, 16);
      uint32_t r32_0 = (uint32_t)__shfl_xor((int)oth0, 32);
      uint32_t r32_1 = (uint32_t)__shfl_xor((int)oth1, 32);
      uint32_t r48_0 = (uint32_t)__shfl_xor((int)oth0, 48);
      uint32_t r48_1 = (uint32_t)__shfl_xor((int)oth1, 48);
      uint32_t d0 = (g == 0) ? own0 : (g == 1) ? r48_0 : (g == 2) ? r32_0 : r16_0;
      uint32_t d1 = (g == 0) ? own1 : (g == 1) ? r48_1 : (g == 2) ? r32_1 : r16_1;
      uint32_t d2 = (g == 0) ? r16_0 : (g == 1) ? r32_0 : (g == 2) ? r48_0 : own0;
      uint32_t d3 = (g == 0) ? r16_1 : (g == 1) ? r32_1 : (g == 2) ? r48_1 : own1;
      union { uint32_t u4[4]; half8v h; } pa;
      pa.u4[0] = d0; pa.u4[1] = d1; pa.u4[2] = d2; pa.u4[3] = d3;
      __builtin_amdgcn_s_setprio(1);
#pragma unroll
      for (int nio = 0; nio < 8; ++nio) {
        int r = nio * 16 + li;
        int key = ((r >> 3) ^ r) & 7;
        half8v bv = *(const half8v*)(Vt + r * 128 + (((kk * 4 + g) ^ key) << 4));
        oacc[nio] = __builtin_amdgcn_mfma_f32_16x16x32_f16(pa.h, bv, oacc[nio], 0, 0, 0);
      }
      __builtin_amdgcn_s_setprio(0);
    }
  }
  float rinv[4];
#pragma unroll
  for (int j = 0; j < 4; ++j)
    rinv[j] = 1.0f / __shfl(lrow, (lane & 48) | (4 * g + j));
  _Float16* Ob = Oa + (size_t)(b * SEQ + qt * 64 + w * 16) * DIM + h * HDIM;
#pragma unroll
  for (int j = 0; j < 4; ++j)
#pragma unroll
    for (int nio = 0; nio < 8; ++nio)
      Ob[(size_t)(4 * g + j) * DIM + nio * 16 + li] = (_Float16)(oacc[nio][j] * rinv[j]);
}

// ---------------- launcher ----------------
extern "C" void kernel_launch(void* const* d_in, const int* in_sizes, int n_in,
                              void* d_out, int out_size, void* d_ws, size_t ws_size,
                              hipStream_t stream) {
  const float* x   = (const float*)d_in[0];
  const float* fc  = (const float*)d_in[1];
  const float* wq  = (const float*)d_in[2];
  const float* wk  = (const float*)d_in[3];
  const float* wv  = (const float*)d_in[4];
  const float* wo  = (const float*)d_in[5];
  const float* qnw = (const float*)d_in[6];
  const float* qnb = (const float*)d_in[7];
  const float* knw = (const float*)d_in[8];
  const float* knb = (const float*)d_in[9];
  float* out = (float*)d_out;
  (void)in_sizes; (void)n_in; (void)out_size;

  const size_t MB = 1024 * 1024;
  if (ws_size < 128 * MB) return;
  char* ws = (char*)d_ws;
  _Float16* x_h    = (_Float16*)(ws + 0);        // 32 MB [4096,4096]
  _Float16* wqkv_h = (_Float16*)(ws + 32 * MB);  // 48 MB [6144,4096] (wq|wk|wv)
  _Float16* wk_h   = (_Float16*)(ws + 64 * MB);
  _Float16* wv_h   = (_Float16*)(ws + 72 * MB);
  _Float16* qkv_h  = (_Float16*)(ws + 80 * MB);  // 48 MB [4096,6144]
  _Float16* wo_h   = wqkv_h;                     // reuse after QKV GEMM
  _Float16* ao_h   = x_h;                        // reuse after QKV GEMM

  cvt_kernel<<<2048, 256, 0, stream>>>(x,  x_h,    (MROWS * DIM) / 8);
  cvt_kernel<<<2048, 256, 0, stream>>>(wq, wqkv_h, (DIM * DIM) / 8);
  cvt_kernel<<<1024, 256, 0, stream>>>(wk, wk_h,   (1024 * DIM) / 8);
  cvt_kernel<<<1024, 256, 0, stream>>>(wv, wv_h,   (1024 * DIM) / 8);

  // QKV GEMM: M=4096, N=6144, K=4096 -> grid 16*24 = 384 (%8==0)
  gemm256<1><<<(MROWS / 256) * (QKV_N / 256), 512, 0, stream>>>(x_h, wqkv_h, qkv_h,
                                                                QKV_N, DIM, QKV_N / 256);

  cvt_kernel<<<2048, 256, 0, stream>>>(wo, wo_h, (DIM * DIM) / 8);

  ln_rope<4096><<<MROWS, 256, 0, stream>>>(qkv_h,        QKV_N, qnw, qnb, fc);
  ln_rope<1024><<<MROWS, 256, 0, stream>>>(qkv_h + KOFF, QKV_N, knw, knb, fc);

  attn_kernel<<<NBATCH * NHEAD * (SEQ / 64), 256, 0, stream>>>(qkv_h, ao_h);

  // out proj: M=4096, N=4096, K=4096 -> grid 16*16 = 256 (%8==0)
  gemm256<0><<<(MROWS / 256) * (DIM / 256), 512, 0, stream>>>(ao_h, wo_h, out,
                                                              DIM, DIM, DIM / 256);
}